// Round 9
// baseline (94.271 us; speedup 1.0000x reference)
//
#include <hip/hip_runtime.h>
#include <hip/hip_bf16.h>

// BilinearPooling: out[b, i*2048+j] = xp[b,i]*yp[b,j] / max(||xp_b||*||yp_b||, eps)
// where xp = x @ W^T, yp = y @ W^T.  B=32, D_IN=1024, D_OUT=2048, fp32.
// ||outer(u,v)||_F = ||u||*||v||  ->  never materialize z before normalizing.
//
// Ladder: 111.3 (R1) -> 110.4 (NT, old geom) -> 108.0 (fill-mimic geom)
//      -> 93.8 (fill-mimic + NT: L2 write-allocate bypass was the writer gap).
// Writer now ~6.4-6.5 TB/s vs fill 6.6-6.85 on identical 2GiB footprint.
// R9: front-end trim only -- 512-thread reduce, coalesced float4 part stores.

#define BROWS 64       // stacked rows: 32 x-rows then 32 y-rows
#define DIN   1024
#define DOUT  2048
#define OTILE 64
#define LDA   132      // padded LDS leading dim (floats)
#define EPS_N 1e-12f

typedef float fx4 __attribute__((ext_vector_type(4)));  // native vec for NT stores

// ---------------- Kernel 1: partial GEMM  proj_partial[ks][r][o] ----------------
// Thread t owns cols o0 + (t&15)*4 + cc (cc=0..3) and rows (t>>4) + 16*rr.
// -> part epilogue stores one dwordx4 per (rr): coalesced.
template <int KS>
__global__ __launch_bounds__(256) void gemm_partial_k(
    const float* __restrict__ x, const float* __restrict__ y,
    const float* __restrict__ W, float* __restrict__ part)
{
    constexpr int KCHUNK = DIN / KS;
    constexpr int NSTAGE = KCHUNK / 128;

    const int o0 = blockIdx.x * OTILE;
    const int ks = blockIdx.y;
    const int t  = threadIdx.x;

    __shared__ float As[BROWS * LDA];
    __shared__ float Bs[OTILE * LDA];

    const int tr = t >> 4;
    const int tc = t & 15;

    float acc[4][4];
#pragma unroll
    for (int a = 0; a < 4; ++a)
#pragma unroll
        for (int b = 0; b < 4; ++b) acc[a][b] = 0.f;

    for (int st = 0; st < NSTAGE; ++st) {
        const int k0 = ks * KCHUNK + st * 128;
        if (st) __syncthreads();
#pragma unroll
        for (int i = 0; i < 8; ++i) {
            int li = t + i * 256;
            int r  = li >> 5;
            int c4 = li & 31;
            const float* src =
                (r < 32 ? x + (size_t)r * DIN : y + (size_t)(r - 32) * DIN)
                + k0 + c4 * 4;
            *(float4*)&As[r * LDA + c4 * 4] = *(const float4*)src;
        }
#pragma unroll
        for (int i = 0; i < 8; ++i) {
            int li = t + i * 256;
            int r  = li >> 5;
            int c4 = li & 31;
            *(float4*)&Bs[r * LDA + c4 * 4] =
                *(const float4*)(W + (size_t)(o0 + r) * DIN + k0 + c4 * 4);
        }
        __syncthreads();

#pragma unroll 8
        for (int k4 = 0; k4 < 32; ++k4) {
            const int k = k4 * 4;
            float4 av[4], bv[4];
#pragma unroll
            for (int rr = 0; rr < 4; ++rr)
                av[rr] = *(float4*)&As[(tr + 16 * rr) * LDA + k];
#pragma unroll
            for (int cc = 0; cc < 4; ++cc)
                bv[cc] = *(float4*)&Bs[(tc * 4 + cc) * LDA + k];
#pragma unroll
            for (int rr = 0; rr < 4; ++rr)
#pragma unroll
                for (int cc = 0; cc < 4; ++cc) {
                    acc[rr][cc] = fmaf(av[rr].x, bv[cc].x, acc[rr][cc]);
                    acc[rr][cc] = fmaf(av[rr].y, bv[cc].y, acc[rr][cc]);
                    acc[rr][cc] = fmaf(av[rr].z, bv[cc].z, acc[rr][cc]);
                    acc[rr][cc] = fmaf(av[rr].w, bv[cc].w, acc[rr][cc]);
                }
        }
    }

#pragma unroll
    for (int rr = 0; rr < 4; ++rr) {
        const int r = tr + 16 * rr;
        float4 v = make_float4(acc[rr][0], acc[rr][1], acc[rr][2], acc[rr][3]);
        *(float4*)&part[((size_t)(ks * BROWS + r)) * DOUT + o0 + tc * 4] = v;
    }
}

// ---------------- Kernel 2: reduce partials + row norms (512 threads) ----------------
template <int KS>
__global__ __launch_bounds__(512) void reduce_rows_k(
    const float* __restrict__ part, float* __restrict__ proj,
    float* __restrict__ norms)
{
    const int r = blockIdx.x;
    const int t = threadIdx.x;          // 0..511, one float4 column-group each
    float4 s = make_float4(0.f, 0.f, 0.f, 0.f);
#pragma unroll
    for (int ks = 0; ks < KS; ++ks) {
        float4 v = *(const float4*)&part[((size_t)(ks * BROWS + r)) * DOUT + t * 4];
        s.x += v.x; s.y += v.y; s.z += v.z; s.w += v.w;
    }
    *(float4*)&proj[(size_t)r * DOUT + t * 4] = s;
    float ss = s.x * s.x + s.y * s.y + s.z * s.z + s.w * s.w;

#pragma unroll
    for (int m = 32; m >= 1; m >>= 1) ss += __shfl_xor(ss, m, 64);
    __shared__ float red[8];
    const int lane = t & 63, wv = t >> 6;
    if (lane == 0) red[wv] = ss;
    __syncthreads();
    if (t == 0) {
        float tot = 0.f;
#pragma unroll
        for (int w = 0; w < 8; ++w) tot += red[w];
        norms[r] = sqrtf(tot);
    }
}

// ---------------- Kernel 3: fill-mimic writer + nontemporal store ----------------
__global__ __launch_bounds__(256) void outer_write_fill_nt(
    const float* __restrict__ proj, const float* __restrict__ norms,
    float* __restrict__ out)
{
    const int  t  = threadIdx.x;
    const unsigned g4 = (blockIdx.x << 8) + t;
    const int  j4 = g4 & 511;
    const unsigned bi = g4 >> 9;       // b*2048 + i  (block-uniform)
    const int  i  = bi & 2047;
    const int  b  = bi >> 11;

    const float s  = 1.0f / fmaxf(norms[b] * norms[32 + b], EPS_N);
    const float xv = proj[(size_t)b * DOUT + i] * s;
    const float4 yv = *(const float4*)&proj[(size_t)(32 + b) * DOUT + j4 * 4];

    fx4 o = { xv * yv.x, xv * yv.y, xv * yv.z, xv * yv.w };
    __builtin_nontemporal_store(o, (fx4*)out + g4);
}

// ---------------- launch ----------------
template <int KS>
static void run_pipeline(const float* x, const float* y, const float* W,
                         float* out, float* ws, hipStream_t stream)
{
    float* part  = ws;
    float* proj  = part + (size_t)KS * BROWS * DOUT;
    float* norms = proj + (size_t)BROWS * DOUT;
    gemm_partial_k<KS><<<dim3(DOUT / OTILE, KS), 256, 0, stream>>>(x, y, W, part);
    reduce_rows_k<KS><<<BROWS, 512, 0, stream>>>(part, proj, norms);
    outer_write_fill_nt<<<131072, 256, 0, stream>>>(proj, norms, out);
}

extern "C" void kernel_launch(void* const* d_in, const int* in_sizes, int n_in,
                              void* d_out, int out_size, void* d_ws, size_t ws_size,
                              hipStream_t stream)
{
    const float* x = (const float*)d_in[0];
    const float* y = (const float*)d_in[1];
    const float* W = (const float*)d_in[2];
    float* out = (float*)d_out;
    float* ws  = (float*)d_ws;

    const size_t need8 = ((size_t)8 * BROWS * DOUT + (size_t)BROWS * DOUT + 64) * sizeof(float);
    const size_t need4 = ((size_t)4 * BROWS * DOUT + (size_t)BROWS * DOUT + 64) * sizeof(float);

    if (ws_size >= need8)
        run_pipeline<8>(x, y, W, out, ws, stream);
    else if (ws_size >= need4)
        run_pipeline<4>(x, y, W, out, ws, stream);
    else
        run_pipeline<1>(x, y, W, out, ws, stream);
}